// Round 7
// baseline (423.503 us; speedup 1.0000x reference)
//
#include <hip/hip_runtime.h>
#include <math.h>
#include <stdint.h>

#define B_ 2
#define S_ 1024
#define D_ 1024
#define H_ 2048
#define E_ 8
#define TOK_ (B_*S_)      // 2048 tokens
#define N1_ (2*H_)        // 4096
#define PAIRS_ (TOK_*2)   // 4096 (token, expert-slot) pairs
#define CAP_ (E_*TOK_)    // 16384 capacity rows (row = e*2048 + slot)
#define MAXTILES_ 40      // max sum of ceil(cnt_e/128) = 32 + 7

typedef float f32x4 __attribute__((ext_vector_type(4)));
typedef short short8 __attribute__((ext_vector_type(8)));

__device__ __forceinline__ unsigned short f2bf(float f) {
  unsigned int u = __float_as_uint(f);
  u += 0x7fffu + ((u >> 16) & 1u);   // RNE
  return (unsigned short)(u >> 16);
}
__device__ __forceinline__ float bf2f(unsigned short u) {
  return __uint_as_float(((unsigned int)u) << 16);
}

// ---------------------------------------------------------------------------
// Fused weight transposes v3: 256k x 64n tiles for DRAM write locality.
// v1/v2 (64x64) were stuck at 2.2 TB/s with 128B scattered dst writes; here
// each dst row receives a 256-element (512 B) contiguous k-segment, and each
// wave-instruction stores 512 B contiguous (4x the row locality).
// Reg-staged load converts fp32->bf16 immediately; LDS packs k-pairs in uints:
//   L[n][pr] = { bf16(src[2pr][n]), bf16(src[2pr+1][n]) }, pad 129 (2-way max
//   on the write phase). Write-out streams uint2 (= ushort4 of k) per lane.
// ---------------------------------------------------------------------------
__device__ __forceinline__ void transpose_tile_v3(
    const float* __restrict__ src, unsigned short* __restrict__ dst,
    int Rk, int C, int e, int kb, int nb, int tid)
{
  __shared__ unsigned int L[64 * 129];   // 33 KB
  const int r0 = kb * 256, c0 = nb * 64;
  const float* s = src + (size_t)e * Rk * C + (size_t)r0 * C + c0;
  unsigned short* d = dst + (size_t)e * Rk * C + (size_t)c0 * Rk + r0;
#pragma unroll
  for (int i = 0; i < 8; ++i) {
    int idx = i * 256 + tid;
    int pr = idx >> 4;                  // k-pair index 0..127
    int c4 = (idx & 15) * 4;            // n col group
    float4 a = *(const float4*)&s[(size_t)(pr * 2) * C + c4];
    float4 b = *(const float4*)&s[(size_t)(pr * 2 + 1) * C + c4];
    L[(c4 + 0) * 129 + pr] = (unsigned int)f2bf(a.x) | ((unsigned int)f2bf(b.x) << 16);
    L[(c4 + 1) * 129 + pr] = (unsigned int)f2bf(a.y) | ((unsigned int)f2bf(b.y) << 16);
    L[(c4 + 2) * 129 + pr] = (unsigned int)f2bf(a.z) | ((unsigned int)f2bf(b.z) << 16);
    L[(c4 + 3) * 129 + pr] = (unsigned int)f2bf(a.w) | ((unsigned int)f2bf(b.w) << 16);
  }
  __syncthreads();
#pragma unroll
  for (int i = 0; i < 16; ++i) {
    int g = i * 256 + tid;
    int n = g >> 6;                     // dst-row within tile (wave-uniform)
    int k4 = g & 63;                    // ushort4 group along k
    uint2 o;
    o.x = L[n * 129 + k4 * 2];
    o.y = L[n * 129 + k4 * 2 + 1];
    *(uint2*)&d[(size_t)n * Rk + k4 * 4] = o;
  }
}

// w12: Rk=1024 (k), C=4096 (n): kb 0..3, nb 0..63 -> 256/e -> 2048 blocks
// w3:  Rk=2048 (k), C=1024 (n): kb 0..7, nb 0..15 -> 128/e -> 1024 blocks
__global__ __launch_bounds__(256) void transpose_all_kernel(
    const float* __restrict__ w12, const float* __restrict__ w3,
    unsigned short* __restrict__ w12t, unsigned short* __restrict__ w3t,
    int* __restrict__ counts)
{
  const int bid = blockIdx.x, tid = threadIdx.x;
  if (bid == 0 && tid < E_) counts[tid] = 0;
  if (bid < 2048) {
    int e = bid >> 8, rem = bid & 255;
    transpose_tile_v3(w12, w12t, D_, N1_, e, rem >> 6, rem & 63, tid);
  } else {
    int b2 = bid - 2048;
    int e = b2 >> 7, rem = b2 & 127;
    transpose_tile_v3(w3, w3t, H_, D_, e, rem >> 4, rem & 15, tid);
  }
}

// ---------------------------------------------------------------------------
// Router + fused pack: one wave per token. Computes logits (fp32 exact),
// sigmoid, top-2, slot assignment (capacity layout: row = e*2048 + slot),
// then writes the token's bf16 row into px for BOTH selected experts straight
// from the registers already holding x (no second read of x, no pack kernel).
// ---------------------------------------------------------------------------
__global__ __launch_bounds__(256) void router_pack_kernel(
    const float* __restrict__ x, const float* __restrict__ rw,
    const float* __restrict__ rb, int* __restrict__ counts,
    int* __restrict__ expert_of, int* __restrict__ slot_of,
    float* __restrict__ w_of, float* __restrict__ tok_ssq,
    unsigned short* __restrict__ px)
{
  const int wave = threadIdx.x >> 6, lane = threadIdx.x & 63;
  const int t = blockIdx.x * 4 + wave;   // one wave per token
  const float4* x4 = (const float4*)(x + (size_t)t * D_);
  const float4* rw4 = (const float4*)rw;
  float4 xv[4];
  float acc[E_];
#pragma unroll
  for (int e = 0; e < E_; ++e) acc[e] = 0.f;
#pragma unroll
  for (int d4 = 0; d4 < 4; ++d4) {
    int idx = d4 * 64 + lane;
    xv[d4] = x4[idx];
#pragma unroll
    for (int e = 0; e < E_; ++e) {
      float4 wv = rw4[e * (D_ / 4) + idx];
      acc[e] += xv[d4].x * wv.x + xv[d4].y * wv.y + xv[d4].z * wv.z + xv[d4].w * wv.w;
    }
  }
#pragma unroll
  for (int e = 0; e < E_; ++e) {
    float v = acc[e];
#pragma unroll
    for (int sh = 32; sh > 0; sh >>= 1) v += __shfl_xor(v, sh, 64);
    acc[e] = v;
  }
  int r1v = 0, r2v = 0;
  if (lane == 0) {
    float logits[E_], sc[E_], ssq = 0.f;
#pragma unroll
    for (int e = 0; e < E_; ++e) {
      logits[e] = acc[e] + rb[e];
      ssq += logits[e] * logits[e];
      sc[e] = 1.f / (1.f + __expf(-logits[e]));
    }
    tok_ssq[t] = ssq;
    int i1 = 0;
#pragma unroll
    for (int e = 1; e < E_; ++e) if (sc[e] > sc[i1]) i1 = e;     // ties -> low idx
    int i2 = (i1 == 0) ? 1 : 0;
#pragma unroll
    for (int e = 0; e < E_; ++e)
      if (e != i1 && e != i2 && sc[e] > sc[i2]) i2 = e;
    float v1 = sc[i1], v2 = sc[i2];
    float inv = 1.f / (v1 + v2 + 1e-6f);
    int s1 = atomicAdd(&counts[i1], 1);
    int s2 = atomicAdd(&counts[i2], 1);
    expert_of[t * 2]     = i1; slot_of[t * 2]     = s1; w_of[t * 2]     = v1 * inv;
    expert_of[t * 2 + 1] = i2; slot_of[t * 2 + 1] = s2; w_of[t * 2 + 1] = v2 * inv;
    r1v = i1 * TOK_ + s1;
    r2v = i2 * TOK_ + s2;
  }
  const int r1 = __shfl(r1v, 0), r2 = __shfl(r2v, 0);
#pragma unroll
  for (int d4 = 0; d4 < 4; ++d4) {
    int idx = d4 * 64 + lane;
    ushort4 o;
    o.x = f2bf(xv[d4].x); o.y = f2bf(xv[d4].y);
    o.z = f2bf(xv[d4].z); o.w = f2bf(xv[d4].w);
    *(ushort4*)&px[(size_t)r1 * D_ + idx * 4] = o;
    *(ushort4*)&px[(size_t)r2 * D_ + idx * 4] = o;
  }
}

// meta: compacted tile table (capacity layout => no offsets), pair_row map,
// aux-loss reduction.
__global__ __launch_bounds__(256) void meta_kernel(
    const int* __restrict__ counts, const float* __restrict__ tok_ssq,
    const int* __restrict__ expert_of, const int* __restrict__ slot_of,
    int* __restrict__ tile_e, int* __restrict__ tile_m0,
    int* __restrict__ pair_row, float* __restrict__ out_aux)
{
  if (threadIdx.x == 0) {
    int nt = 0;
    for (int e = 0; e < E_; ++e) {
      for (int m0 = 0; m0 < counts[e]; m0 += 128) {
        tile_e[nt] = e; tile_m0[nt] = m0; ++nt;
      }
    }
    for (; nt < MAXTILES_; ++nt) tile_e[nt] = -1;
  }
  for (int p = threadIdx.x; p < PAIRS_; p += 256)
    pair_row[p] = expert_of[p] * TOK_ + slot_of[p];
  __shared__ float sm[256];
  float s = 0.f;
  for (int i = threadIdx.x; i < TOK_; i += 256) s += tok_ssq[i];
  sm[threadIdx.x] = s;
  __syncthreads();
  for (int h = 128; h > 0; h >>= 1) {
    if (threadIdx.x < h) sm[threadIdx.x] += sm[threadIdx.x + h];
    __syncthreads();
  }
  if (threadIdx.x == 0) *out_aux = 0.01f * sm[0] / (float)(TOK_ * E_);
}

// ---------------------------------------------------------------------------
// GEMM staging, BK=64: 128-row x 64-col bf16 tile via global_load_lds w=16.
// LDS layout [row][64] contiguous; XOR swizzle on SOURCE segment:
//   LDS[row][s] = G[row][s ^ (row&7)]  (global_load_lds dest is lane-implicit)
// Frag read of G[row][j*32+lk*8..+8] -> LDS[row][(j*4+lk)^(row&7)] (2-way max).
// ---------------------------------------------------------------------------
__device__ __forceinline__ void stage64(const unsigned short* gbase, int gstride,
                                        unsigned short* sbase, int kk,
                                        int wave, int lane)
{
  const int rw = lane >> 3;                 // 0..7
  const int seg = (lane & 7) ^ rw;          // swizzled source segment
#pragma unroll
  for (int c = 0; c < 4; ++c) {
    int row = wave * 8 + c * 32 + rw;
    const unsigned short* g = gbase + (size_t)row * gstride + kk + seg * 8;
    unsigned short* s = sbase + (size_t)(wave * 8 + c * 32) * 64;  // wave-uniform
    __builtin_amdgcn_global_load_lds(
        (const __attribute__((address_space(1))) void*)g,
        (__attribute__((address_space(3))) void*)s, 16, 0, 0);
  }
}

__device__ __forceinline__ void stage64_clamped(const unsigned short* gbase, int gstride,
                                                int row0, int rowmax,
                                                unsigned short* sbase, int kk,
                                                int wave, int lane)
{
  const int rw = lane >> 3;
  const int seg = (lane & 7) ^ rw;
#pragma unroll
  for (int c = 0; c < 4; ++c) {
    int row = row0 + wave * 8 + c * 32 + rw;
    row = (row < rowmax) ? row : rowmax - 1;
    const unsigned short* g = gbase + (size_t)row * gstride + kk + seg * 8;
    unsigned short* s = sbase + (size_t)(wave * 8 + c * 32) * 64;
    __builtin_amdgcn_global_load_lds(
        (const __attribute__((address_space(1))) void*)g,
        (__attribute__((address_space(3))) void*)s, 16, 0, 0);
  }
}

__device__ __forceinline__ short8 read_frag64(const unsigned short* smem, int row,
                                              int j, int lk) {
  const int s = (j * 4 + lk) ^ (row & 7);
  return *(const short8*)&smem[row * 64 + s * 8];
}

// ---------------------------------------------------------------------------
// GEMM1 + fused SwiGLU (round-0 body): 128 rows x 128 hidden cols, 4 waves
// 2x2, single-buffered LDS (48 KB), latency hidden by cross-block TLP.
// Capacity layout: A rows at e*2048 + m0.., hid rows likewise.
// ---------------------------------------------------------------------------
__global__ __launch_bounds__(256, 2) void gemm1_kernel(
    const unsigned short* __restrict__ px, const unsigned short* __restrict__ w12t,
    unsigned short* __restrict__ hid, const int* __restrict__ counts,
    const int* __restrict__ tile_e, const int* __restrict__ tile_m0)
{
  const int ti = blockIdx.y, nt = blockIdx.x;
  const int e = tile_e[ti];
  if (e < 0) return;
  const int m0 = tile_m0[ti];
  const int cnt = counts[e];
  const int off = e * TOK_;
  const int tid = threadIdx.x;
  const int wave = tid >> 6, lane = tid & 63;
  const int wm = wave >> 1, wn = wave & 1;
  const int lr = lane & 15, lk = lane >> 4;

  __shared__ __align__(16) unsigned short As[128 * 64];
  __shared__ __align__(16) unsigned short B1s[128 * 64];
  __shared__ __align__(16) unsigned short B2s[128 * 64];

  f32x4 zero = {0.f, 0.f, 0.f, 0.f};
  f32x4 acc1[4][4], acc2[4][4];
#pragma unroll
  for (int mi = 0; mi < 4; ++mi)
#pragma unroll
    for (int ni = 0; ni < 4; ++ni) { acc1[mi][ni] = zero; acc2[mi][ni] = zero; }

  const unsigned short* B1base = w12t + ((size_t)e * N1_ + nt * 128) * D_;
  const unsigned short* B2base = w12t + ((size_t)e * N1_ + H_ + nt * 128) * D_;

  for (int kk = 0; kk < D_; kk += 64) {
    stage64_clamped(px, D_, off + m0, CAP_, As, kk, wave, lane);
    stage64(B1base, D_, B1s, kk, wave, lane);
    stage64(B2base, D_, B2s, kk, wave, lane);
    __syncthreads();
#pragma unroll
    for (int j = 0; j < 2; ++j) {
      short8 a[4], b1[4], b2[4];
#pragma unroll
      for (int i = 0; i < 4; ++i) {
        a[i]  = read_frag64(As,  wm * 64 + i * 16 + lr, j, lk);
        b1[i] = read_frag64(B1s, wn * 64 + i * 16 + lr, j, lk);
        b2[i] = read_frag64(B2s, wn * 64 + i * 16 + lr, j, lk);
      }
#pragma unroll
      for (int mi = 0; mi < 4; ++mi)
#pragma unroll
        for (int ni = 0; ni < 4; ++ni) {
          acc1[mi][ni] = __builtin_amdgcn_mfma_f32_16x16x32_bf16(a[mi], b1[ni], acc1[mi][ni], 0, 0, 0);
          acc2[mi][ni] = __builtin_amdgcn_mfma_f32_16x16x32_bf16(a[mi], b2[ni], acc2[mi][ni], 0, 0, 0);
        }
    }
    __syncthreads();
  }

  // epilogue: SwiGLU + bf16 store (C/D layout: col=lane&15, row=(lane>>4)*4+r)
#pragma unroll
  for (int mi = 0; mi < 4; ++mi)
#pragma unroll
    for (int r = 0; r < 4; ++r) {
      int row_local = m0 + wm * 64 + mi * 16 + lk * 4 + r;
      if (row_local < cnt) {
#pragma unroll
        for (int ni = 0; ni < 4; ++ni) {
          int col = nt * 128 + wn * 64 + ni * 16 + lr;
          float v1 = acc1[mi][ni][r];
          float v2 = acc2[mi][ni][r];
          float hval = (v1 / (1.f + __expf(-v1))) * v2;
          hid[(size_t)(off + row_local) * H_ + col] = f2bf(hval);
        }
      }
    }
}

// ---------------------------------------------------------------------------
// GEMM2 (round-0 body): ybuf[ks][row][d] = (hid @ w3t^T) over K-half ks.
// Single-buffered, (256,4): latency hiding via 4-block/CU TLP (measured best).
// ---------------------------------------------------------------------------
__global__ __launch_bounds__(256, 4) void gemm2_kernel(
    const unsigned short* __restrict__ hid, const unsigned short* __restrict__ w3t,
    const int* __restrict__ counts, const int* __restrict__ tile_e,
    const int* __restrict__ tile_m0, unsigned short* __restrict__ ybuf)
{
  const int ti = blockIdx.y, nt = blockIdx.x, ks = blockIdx.z;
  const int e = tile_e[ti];
  if (e < 0) return;
  const int m0 = tile_m0[ti];
  const int cnt = counts[e];
  const int off = e * TOK_;
  const int tid = threadIdx.x;
  const int wave = tid >> 6, lane = tid & 63;
  const int wm = wave >> 1, wn = wave & 1;
  const int lr = lane & 15, lk = lane >> 4;

  __shared__ __align__(16) unsigned short As[128 * 64];
  __shared__ __align__(16) unsigned short Bs[128 * 64];

  f32x4 zero = {0.f, 0.f, 0.f, 0.f};
  f32x4 acc[4][4];
#pragma unroll
  for (int mi = 0; mi < 4; ++mi)
#pragma unroll
    for (int ni = 0; ni < 4; ++ni) acc[mi][ni] = zero;

  const unsigned short* Bbase = w3t + ((size_t)e * D_ + nt * 128) * H_;
  unsigned short* yb = ybuf + (size_t)ks * CAP_ * D_;

  const int k0 = ks * (H_ / 2), k1 = k0 + (H_ / 2);
  for (int kk = k0; kk < k1; kk += 64) {
    stage64_clamped(hid, H_, off + m0, CAP_, As, kk, wave, lane);
    stage64(Bbase, H_, Bs, kk, wave, lane);
    __syncthreads();
#pragma unroll
    for (int j = 0; j < 2; ++j) {
      short8 a[4], b[4];
#pragma unroll
      for (int i = 0; i < 4; ++i) {
        a[i] = read_frag64(As, wm * 64 + i * 16 + lr, j, lk);
        b[i] = read_frag64(Bs, wn * 64 + i * 16 + lr, j, lk);
      }
#pragma unroll
      for (int mi = 0; mi < 4; ++mi)
#pragma unroll
        for (int ni = 0; ni < 4; ++ni)
          acc[mi][ni] = __builtin_amdgcn_mfma_f32_16x16x32_bf16(a[mi], b[ni], acc[mi][ni], 0, 0, 0);
    }
    __syncthreads();
  }

#pragma unroll
  for (int mi = 0; mi < 4; ++mi)
#pragma unroll
    for (int r = 0; r < 4; ++r) {
      int row_local = m0 + wm * 64 + mi * 16 + lk * 4 + r;
      if (row_local < cnt) {
        int g = off + row_local;
#pragma unroll
        for (int ni = 0; ni < 4; ++ni) {
          int col = nt * 128 + wn * 64 + ni * 16 + lr;
          yb[(size_t)g * D_ + col] = f2bf(acc[mi][ni][r]);
        }
      }
    }
}

// ---------------------------------------------------------------------------
// Combine: out[t][d] = w0*(y0[r0][d]+y1[r0][d]) + w1*(y0[r1][d]+y1[r1][d])
// ---------------------------------------------------------------------------
__global__ __launch_bounds__(256) void combine_kernel(
    const unsigned short* __restrict__ ybuf, const int* __restrict__ pair_row,
    const float* __restrict__ w_of, float* __restrict__ out)
{
  const int t = blockIdx.x;
  const int r0 = pair_row[t * 2], r1 = pair_row[t * 2 + 1];
  const float w0 = w_of[t * 2], w1 = w_of[t * 2 + 1];
  const unsigned short* y1p = ybuf + (size_t)CAP_ * D_;
  const int i = threadIdx.x;               // 256 threads x 4 elems
  ushort4 a0 = *(const ushort4*)&ybuf[(size_t)r0 * D_ + i * 4];
  ushort4 b0 = *(const ushort4*)&y1p [(size_t)r0 * D_ + i * 4];
  ushort4 a1 = *(const ushort4*)&ybuf[(size_t)r1 * D_ + i * 4];
  ushort4 b1 = *(const ushort4*)&y1p [(size_t)r1 * D_ + i * 4];
  float4 o;
  o.x = w0 * (bf2f(a0.x) + bf2f(b0.x)) + w1 * (bf2f(a1.x) + bf2f(b1.x));
  o.y = w0 * (bf2f(a0.y) + bf2f(b0.y)) + w1 * (bf2f(a1.y) + bf2f(b1.y));
  o.z = w0 * (bf2f(a0.z) + bf2f(b0.z)) + w1 * (bf2f(a1.z) + bf2f(b1.z));
  o.w = w0 * (bf2f(a0.w) + bf2f(b0.w)) + w1 * (bf2f(a1.w) + bf2f(b1.w));
  ((float4*)out)[(size_t)t * (D_ / 4) + i] = o;
}

// ---------------------------------------------------------------------------
extern "C" void kernel_launch(void* const* d_in, const int* in_sizes, int n_in,
                              void* d_out, int out_size, void* d_ws, size_t ws_size,
                              hipStream_t stream)
{
  const float* x   = (const float*)d_in[0];
  const float* rw  = (const float*)d_in[1];
  const float* rb  = (const float*)d_in[2];
  const float* w12 = (const float*)d_in[3];
  const float* w3  = (const float*)d_in[4];
  float* out = (float*)d_out;

  // workspace layout (~258 MB; capacity layout CAP_=16384 rows)
  char* wsb = (char*)d_ws;
  int*   counts    = (int*)(wsb + 0);                 // 8 ints
  int*   tile_e    = (int*)(wsb + 1024);              // 40 ints
  int*   tile_m0   = (int*)(wsb + 2048);              // 40 ints
  int*   expert_of = (int*)(wsb + 4096);              // 4096 ints (16 KB)
  int*   slot_of   = (int*)(wsb + 4096 + 16384);
  float* w_of      = (float*)(wsb + 4096 + 2 * 16384);
  int*   pair_row  = (int*)(wsb + 4096 + 3 * 16384);
  float* tok_ssq   = (float*)(wsb + 4096 + 4 * 16384);        // 2048 floats
  unsigned short* px   = (unsigned short*)(wsb + ((size_t)1   << 20));   // 32 MB
  unsigned short* hid  = (unsigned short*)(wsb + ((size_t)34  << 20));   // 64 MB
  unsigned short* w12t = (unsigned short*)(wsb + ((size_t)98  << 20));   // 64 MB
  unsigned short* w3t  = (unsigned short*)(wsb + ((size_t)162 << 20));   // 32 MB
  unsigned short* ybuf = (unsigned short*)(wsb + ((size_t)194 << 20));   // 64 MB

  transpose_all_kernel<<<3072, 256, 0, stream>>>(w12, w3, w12t, w3t, counts);
  router_pack_kernel<<<TOK_ / 4, 256, 0, stream>>>(x, rw, rb, counts, expert_of, slot_of, w_of, tok_ssq, px);
  meta_kernel<<<1, 256, 0, stream>>>(counts, tok_ssq, expert_of, slot_of, tile_e, tile_m0, pair_row, out + (size_t)TOK_ * D_);
  gemm1_kernel<<<dim3(16, MAXTILES_), 256, 0, stream>>>(px, w12t, hid, counts, tile_e, tile_m0);
  gemm2_kernel<<<dim3(8, MAXTILES_, 2), 256, 0, stream>>>(hid, w3t, counts, tile_e, tile_m0, ybuf);
  combine_kernel<<<TOK_, 256, 0, stream>>>(ybuf, pair_row, w_of, out);
}

// Round 8
// 417.600 us; speedup vs baseline: 1.0141x; 1.0141x over previous
//
#include <hip/hip_runtime.h>
#include <math.h>
#include <stdint.h>

#define B_ 2
#define S_ 1024
#define D_ 1024
#define H_ 2048
#define E_ 8
#define TOK_ (B_*S_)      // 2048 tokens
#define N1_ (2*H_)        // 4096
#define PAIRS_ (TOK_*2)   // 4096 (token, expert-slot) pairs
#define CAP_ (E_*TOK_)    // 16384 capacity rows (row = e*2048 + slot)
#define MAXTILES_ 40      // max sum of ceil(cnt_e/128) = 32 + 7

typedef float f32x4 __attribute__((ext_vector_type(4)));
typedef short short8 __attribute__((ext_vector_type(8)));

__device__ __forceinline__ unsigned short f2bf(float f) {
  unsigned int u = __float_as_uint(f);
  u += 0x7fffu + ((u >> 16) & 1u);   // RNE
  return (unsigned short)(u >> 16);
}
__device__ __forceinline__ float bf2f(unsigned short u) {
  return __uint_as_float(((unsigned int)u) << 16);
}

// ---------------------------------------------------------------------------
// Fused weight transposes v4: 256k x 128n tiles — BOTH src reads and dst
// writes at 512 B per wave-instruction (v1-v3 ablation showed the 256B read
// strips were the only invariant across all ~92 us variants).
// Reg-staged: thread loads float4 from adjacent k-rows (2kp, 2kp+1), converts
// to bf16, packs k-pairs into uints.  LDS = [128 n][128 kp-uints] (64 KB),
// XOR col-swizzle c = kp ^ (n & 28)  (multiple of 4 -> b128 runs preserved;
// write phase 4-way max, read phase conflict-free).
// Write-out: 32 lanes stream one 512 B dst row (uint4 = 8 k each).
// Block 0 zeroes counts (replaces the hipMemsetAsync dispatch).
// ---------------------------------------------------------------------------
__device__ __forceinline__ void transpose_tile_v4(
    const float* __restrict__ src, unsigned short* __restrict__ dst,
    int Rk, int C, int e, int kb, int nb, int tid)
{
  __shared__ unsigned int L[128 * 128];   // 64 KB
  const int r0 = kb * 256, c0 = nb * 128;
  const float* s = src + (size_t)e * Rk * C + (size_t)r0 * C + c0;
  unsigned short* d = dst + (size_t)e * Rk * C + (size_t)c0 * Rk + r0;
  // load + convert + pack: 4096 units (kp 0..127 x n4 0..31), 8 per thread
#pragma unroll
  for (int i = 0; i < 8; ++i) {
    int u = i * 512 + tid;
    int kp = u >> 5;                    // k-pair 0..127
    int n0 = (u & 31) * 4;              // n group
    float4 a = *(const float4*)&s[(size_t)(kp * 2) * C + n0];
    float4 b = *(const float4*)&s[(size_t)(kp * 2 + 1) * C + n0];
#pragma unroll
    for (int m = 0; m < 4; ++m) {
      int n = n0 + m;
      float av = (m == 0) ? a.x : (m == 1) ? a.y : (m == 2) ? a.z : a.w;
      float bv = (m == 0) ? b.x : (m == 1) ? b.y : (m == 2) ? b.z : b.w;
      L[n * 128 + (kp ^ (n & 28))] =
          (unsigned int)f2bf(av) | ((unsigned int)f2bf(bv) << 16);
    }
  }
  __syncthreads();
  // write-out: 4096 units (n 0..127 x j 0..31), 8 per thread; 16 B per unit
#pragma unroll
  for (int i = 0; i < 8; ++i) {
    int g = i * 512 + tid;
    int n = g >> 5;                     // dst row within tile
    int j = g & 31;                     // uint4 group along k
    uint4 o = *(const uint4*)&L[n * 128 + ((4 * j) ^ (n & 28))];
    *(uint4*)&d[(size_t)n * Rk + j * 8] = o;
  }
}

// w12: Rk=1024, C=4096: kb 0..3, nb 0..31 -> 128/e -> 1024 blocks
// w3:  Rk=2048, C=1024: kb 0..7, nb 0..7  ->  64/e ->  512 blocks
__global__ __launch_bounds__(512) void transpose_all_kernel(
    const float* __restrict__ w12, const float* __restrict__ w3,
    unsigned short* __restrict__ w12t, unsigned short* __restrict__ w3t,
    int* __restrict__ counts)
{
  const int bid = blockIdx.x, tid = threadIdx.x;
  if (bid == 0 && tid < E_) counts[tid] = 0;
  if (bid < 1024) {
    int e = bid >> 7, rem = bid & 127;
    transpose_tile_v4(w12, w12t, D_, N1_, e, rem >> 5, rem & 31, tid);
  } else {
    int b2 = bid - 1024;
    int e = b2 >> 6, rem = b2 & 63;
    transpose_tile_v4(w3, w3t, H_, D_, e, rem >> 3, rem & 7, tid);
  }
}

// ---------------------------------------------------------------------------
// Router + fused pack: one wave per token. Computes logits (fp32 exact),
// sigmoid, top-2, slot assignment (capacity layout: row = e*2048 + slot),
// then writes the token's bf16 row into px for BOTH selected experts straight
// from the registers already holding x (no second read of x, no pack kernel).
// ---------------------------------------------------------------------------
__global__ __launch_bounds__(256) void router_pack_kernel(
    const float* __restrict__ x, const float* __restrict__ rw,
    const float* __restrict__ rb, int* __restrict__ counts,
    int* __restrict__ expert_of, int* __restrict__ slot_of,
    float* __restrict__ w_of, float* __restrict__ tok_ssq,
    unsigned short* __restrict__ px)
{
  const int wave = threadIdx.x >> 6, lane = threadIdx.x & 63;
  const int t = blockIdx.x * 4 + wave;   // one wave per token
  const float4* x4 = (const float4*)(x + (size_t)t * D_);
  const float4* rw4 = (const float4*)rw;
  float4 xv[4];
  float acc[E_];
#pragma unroll
  for (int e = 0; e < E_; ++e) acc[e] = 0.f;
#pragma unroll
  for (int d4 = 0; d4 < 4; ++d4) {
    int idx = d4 * 64 + lane;
    xv[d4] = x4[idx];
#pragma unroll
    for (int e = 0; e < E_; ++e) {
      float4 wv = rw4[e * (D_ / 4) + idx];
      acc[e] += xv[d4].x * wv.x + xv[d4].y * wv.y + xv[d4].z * wv.z + xv[d4].w * wv.w;
    }
  }
#pragma unroll
  for (int e = 0; e < E_; ++e) {
    float v = acc[e];
#pragma unroll
    for (int sh = 32; sh > 0; sh >>= 1) v += __shfl_xor(v, sh, 64);
    acc[e] = v;
  }
  int r1v = 0, r2v = 0;
  if (lane == 0) {
    float logits[E_], sc[E_], ssq = 0.f;
#pragma unroll
    for (int e = 0; e < E_; ++e) {
      logits[e] = acc[e] + rb[e];
      ssq += logits[e] * logits[e];
      sc[e] = 1.f / (1.f + __expf(-logits[e]));
    }
    tok_ssq[t] = ssq;
    int i1 = 0;
#pragma unroll
    for (int e = 1; e < E_; ++e) if (sc[e] > sc[i1]) i1 = e;     // ties -> low idx
    int i2 = (i1 == 0) ? 1 : 0;
#pragma unroll
    for (int e = 0; e < E_; ++e)
      if (e != i1 && e != i2 && sc[e] > sc[i2]) i2 = e;
    float v1 = sc[i1], v2 = sc[i2];
    float inv = 1.f / (v1 + v2 + 1e-6f);
    int s1 = atomicAdd(&counts[i1], 1);
    int s2 = atomicAdd(&counts[i2], 1);
    expert_of[t * 2]     = i1; slot_of[t * 2]     = s1; w_of[t * 2]     = v1 * inv;
    expert_of[t * 2 + 1] = i2; slot_of[t * 2 + 1] = s2; w_of[t * 2 + 1] = v2 * inv;
    r1v = i1 * TOK_ + s1;
    r2v = i2 * TOK_ + s2;
  }
  const int r1 = __shfl(r1v, 0), r2 = __shfl(r2v, 0);
#pragma unroll
  for (int d4 = 0; d4 < 4; ++d4) {
    int idx = d4 * 64 + lane;
    ushort4 o;
    o.x = f2bf(xv[d4].x); o.y = f2bf(xv[d4].y);
    o.z = f2bf(xv[d4].z); o.w = f2bf(xv[d4].w);
    *(ushort4*)&px[(size_t)r1 * D_ + idx * 4] = o;
    *(ushort4*)&px[(size_t)r2 * D_ + idx * 4] = o;
  }
}

// meta: compacted tile table (capacity layout => no offsets), pair_row map,
// aux-loss reduction.
__global__ __launch_bounds__(256) void meta_kernel(
    const int* __restrict__ counts, const float* __restrict__ tok_ssq,
    const int* __restrict__ expert_of, const int* __restrict__ slot_of,
    int* __restrict__ tile_e, int* __restrict__ tile_m0,
    int* __restrict__ pair_row, float* __restrict__ out_aux)
{
  if (threadIdx.x == 0) {
    int nt = 0;
    for (int e = 0; e < E_; ++e) {
      for (int m0 = 0; m0 < counts[e]; m0 += 128) {
        tile_e[nt] = e; tile_m0[nt] = m0; ++nt;
      }
    }
    for (; nt < MAXTILES_; ++nt) tile_e[nt] = -1;
  }
  for (int p = threadIdx.x; p < PAIRS_; p += 256)
    pair_row[p] = expert_of[p] * TOK_ + slot_of[p];
  __shared__ float sm[256];
  float s = 0.f;
  for (int i = threadIdx.x; i < TOK_; i += 256) s += tok_ssq[i];
  sm[threadIdx.x] = s;
  __syncthreads();
  for (int h = 128; h > 0; h >>= 1) {
    if (threadIdx.x < h) sm[threadIdx.x] += sm[threadIdx.x + h];
    __syncthreads();
  }
  if (threadIdx.x == 0) *out_aux = 0.01f * sm[0] / (float)(TOK_ * E_);
}

// ---------------------------------------------------------------------------
// GEMM staging, BK=64: 128-row x 64-col bf16 tile via global_load_lds w=16.
// LDS layout [row][64] contiguous; XOR swizzle on SOURCE segment:
//   LDS[row][s] = G[row][s ^ (row&7)]  (global_load_lds dest is lane-implicit)
// Frag read of G[row][j*32+lk*8..+8] -> LDS[row][(j*4+lk)^(row&7)] (2-way max).
// ---------------------------------------------------------------------------
__device__ __forceinline__ void stage64(const unsigned short* gbase, int gstride,
                                        unsigned short* sbase, int kk,
                                        int wave, int lane)
{
  const int rw = lane >> 3;                 // 0..7
  const int seg = (lane & 7) ^ rw;          // swizzled source segment
#pragma unroll
  for (int c = 0; c < 4; ++c) {
    int row = wave * 8 + c * 32 + rw;
    const unsigned short* g = gbase + (size_t)row * gstride + kk + seg * 8;
    unsigned short* s = sbase + (size_t)(wave * 8 + c * 32) * 64;  // wave-uniform
    __builtin_amdgcn_global_load_lds(
        (const __attribute__((address_space(1))) void*)g,
        (__attribute__((address_space(3))) void*)s, 16, 0, 0);
  }
}

__device__ __forceinline__ void stage64_clamped(const unsigned short* gbase, int gstride,
                                                int row0, int rowmax,
                                                unsigned short* sbase, int kk,
                                                int wave, int lane)
{
  const int rw = lane >> 3;
  const int seg = (lane & 7) ^ rw;
#pragma unroll
  for (int c = 0; c < 4; ++c) {
    int row = row0 + wave * 8 + c * 32 + rw;
    row = (row < rowmax) ? row : rowmax - 1;
    const unsigned short* g = gbase + (size_t)row * gstride + kk + seg * 8;
    unsigned short* s = sbase + (size_t)(wave * 8 + c * 32) * 64;
    __builtin_amdgcn_global_load_lds(
        (const __attribute__((address_space(1))) void*)g,
        (__attribute__((address_space(3))) void*)s, 16, 0, 0);
  }
}

__device__ __forceinline__ short8 read_frag64(const unsigned short* smem, int row,
                                              int j, int lk) {
  const int s = (j * 4 + lk) ^ (row & 7);
  return *(const short8*)&smem[row * 64 + s * 8];
}

// ---------------------------------------------------------------------------
// GEMM1 + fused SwiGLU (round-0 body): 128 rows x 128 hidden cols, 4 waves
// 2x2, single-buffered LDS (48 KB), latency hidden by cross-block TLP.
// Capacity layout: A rows at e*2048 + m0.., hid rows likewise.
// ---------------------------------------------------------------------------
__global__ __launch_bounds__(256, 2) void gemm1_kernel(
    const unsigned short* __restrict__ px, const unsigned short* __restrict__ w12t,
    unsigned short* __restrict__ hid, const int* __restrict__ counts,
    const int* __restrict__ tile_e, const int* __restrict__ tile_m0)
{
  const int ti = blockIdx.y, nt = blockIdx.x;
  const int e = tile_e[ti];
  if (e < 0) return;
  const int m0 = tile_m0[ti];
  const int cnt = counts[e];
  const int off = e * TOK_;
  const int tid = threadIdx.x;
  const int wave = tid >> 6, lane = tid & 63;
  const int wm = wave >> 1, wn = wave & 1;
  const int lr = lane & 15, lk = lane >> 4;

  __shared__ __align__(16) unsigned short As[128 * 64];
  __shared__ __align__(16) unsigned short B1s[128 * 64];
  __shared__ __align__(16) unsigned short B2s[128 * 64];

  f32x4 zero = {0.f, 0.f, 0.f, 0.f};
  f32x4 acc1[4][4], acc2[4][4];
#pragma unroll
  for (int mi = 0; mi < 4; ++mi)
#pragma unroll
    for (int ni = 0; ni < 4; ++ni) { acc1[mi][ni] = zero; acc2[mi][ni] = zero; }

  const unsigned short* B1base = w12t + ((size_t)e * N1_ + nt * 128) * D_;
  const unsigned short* B2base = w12t + ((size_t)e * N1_ + H_ + nt * 128) * D_;

  for (int kk = 0; kk < D_; kk += 64) {
    stage64_clamped(px, D_, off + m0, CAP_, As, kk, wave, lane);
    stage64(B1base, D_, B1s, kk, wave, lane);
    stage64(B2base, D_, B2s, kk, wave, lane);
    __syncthreads();
#pragma unroll
    for (int j = 0; j < 2; ++j) {
      short8 a[4], b1[4], b2[4];
#pragma unroll
      for (int i = 0; i < 4; ++i) {
        a[i]  = read_frag64(As,  wm * 64 + i * 16 + lr, j, lk);
        b1[i] = read_frag64(B1s, wn * 64 + i * 16 + lr, j, lk);
        b2[i] = read_frag64(B2s, wn * 64 + i * 16 + lr, j, lk);
      }
#pragma unroll
      for (int mi = 0; mi < 4; ++mi)
#pragma unroll
        for (int ni = 0; ni < 4; ++ni) {
          acc1[mi][ni] = __builtin_amdgcn_mfma_f32_16x16x32_bf16(a[mi], b1[ni], acc1[mi][ni], 0, 0, 0);
          acc2[mi][ni] = __builtin_amdgcn_mfma_f32_16x16x32_bf16(a[mi], b2[ni], acc2[mi][ni], 0, 0, 0);
        }
    }
    __syncthreads();
  }

  // epilogue: SwiGLU + bf16 store (C/D layout: col=lane&15, row=(lane>>4)*4+r)
#pragma unroll
  for (int mi = 0; mi < 4; ++mi)
#pragma unroll
    for (int r = 0; r < 4; ++r) {
      int row_local = m0 + wm * 64 + mi * 16 + lk * 4 + r;
      if (row_local < cnt) {
#pragma unroll
        for (int ni = 0; ni < 4; ++ni) {
          int col = nt * 128 + wn * 64 + ni * 16 + lr;
          float v1 = acc1[mi][ni][r];
          float v2 = acc2[mi][ni][r];
          float hval = (v1 / (1.f + __expf(-v1))) * v2;
          hid[(size_t)(off + row_local) * H_ + col] = f2bf(hval);
        }
      }
    }
}

// ---------------------------------------------------------------------------
// GEMM2 (round-0 body): ybuf[ks][row][d] = (hid @ w3t^T) over K-half ks.
// Single-buffered, (256,4): latency hiding via 4-block/CU TLP (measured best).
// ---------------------------------------------------------------------------
__global__ __launch_bounds__(256, 4) void gemm2_kernel(
    const unsigned short* __restrict__ hid, const unsigned short* __restrict__ w3t,
    const int* __restrict__ counts, const int* __restrict__ tile_e,
    const int* __restrict__ tile_m0, unsigned short* __restrict__ ybuf)
{
  const int ti = blockIdx.y, nt = blockIdx.x, ks = blockIdx.z;
  const int e = tile_e[ti];
  if (e < 0) return;
  const int m0 = tile_m0[ti];
  const int cnt = counts[e];
  const int off = e * TOK_;
  const int tid = threadIdx.x;
  const int wave = tid >> 6, lane = tid & 63;
  const int wm = wave >> 1, wn = wave & 1;
  const int lr = lane & 15, lk = lane >> 4;

  __shared__ __align__(16) unsigned short As[128 * 64];
  __shared__ __align__(16) unsigned short Bs[128 * 64];

  f32x4 zero = {0.f, 0.f, 0.f, 0.f};
  f32x4 acc[4][4];
#pragma unroll
  for (int mi = 0; mi < 4; ++mi)
#pragma unroll
    for (int ni = 0; ni < 4; ++ni) acc[mi][ni] = zero;

  const unsigned short* Bbase = w3t + ((size_t)e * D_ + nt * 128) * H_;
  unsigned short* yb = ybuf + (size_t)ks * CAP_ * D_;

  const int k0 = ks * (H_ / 2), k1 = k0 + (H_ / 2);
  for (int kk = k0; kk < k1; kk += 64) {
    stage64_clamped(hid, H_, off + m0, CAP_, As, kk, wave, lane);
    stage64(Bbase, H_, Bs, kk, wave, lane);
    __syncthreads();
#pragma unroll
    for (int j = 0; j < 2; ++j) {
      short8 a[4], b[4];
#pragma unroll
      for (int i = 0; i < 4; ++i) {
        a[i] = read_frag64(As, wm * 64 + i * 16 + lr, j, lk);
        b[i] = read_frag64(Bs, wn * 64 + i * 16 + lr, j, lk);
      }
#pragma unroll
      for (int mi = 0; mi < 4; ++mi)
#pragma unroll
        for (int ni = 0; ni < 4; ++ni)
          acc[mi][ni] = __builtin_amdgcn_mfma_f32_16x16x32_bf16(a[mi], b[ni], acc[mi][ni], 0, 0, 0);
    }
    __syncthreads();
  }

#pragma unroll
  for (int mi = 0; mi < 4; ++mi)
#pragma unroll
    for (int r = 0; r < 4; ++r) {
      int row_local = m0 + wm * 64 + mi * 16 + lk * 4 + r;
      if (row_local < cnt) {
        int g = off + row_local;
#pragma unroll
        for (int ni = 0; ni < 4; ++ni) {
          int col = nt * 128 + wn * 64 + ni * 16 + lr;
          yb[(size_t)g * D_ + col] = f2bf(acc[mi][ni][r]);
        }
      }
    }
}

// ---------------------------------------------------------------------------
// Combine: out[t][d] = w0*(y0[r0][d]+y1[r0][d]) + w1*(y0[r1][d]+y1[r1][d])
// ---------------------------------------------------------------------------
__global__ __launch_bounds__(256) void combine_kernel(
    const unsigned short* __restrict__ ybuf, const int* __restrict__ pair_row,
    const float* __restrict__ w_of, float* __restrict__ out)
{
  const int t = blockIdx.x;
  const int r0 = pair_row[t * 2], r1 = pair_row[t * 2 + 1];
  const float w0 = w_of[t * 2], w1 = w_of[t * 2 + 1];
  const unsigned short* y1p = ybuf + (size_t)CAP_ * D_;
  const int i = threadIdx.x;               // 256 threads x 4 elems
  ushort4 a0 = *(const ushort4*)&ybuf[(size_t)r0 * D_ + i * 4];
  ushort4 b0 = *(const ushort4*)&y1p [(size_t)r0 * D_ + i * 4];
  ushort4 a1 = *(const ushort4*)&ybuf[(size_t)r1 * D_ + i * 4];
  ushort4 b1 = *(const ushort4*)&y1p [(size_t)r1 * D_ + i * 4];
  float4 o;
  o.x = w0 * (bf2f(a0.x) + bf2f(b0.x)) + w1 * (bf2f(a1.x) + bf2f(b1.x));
  o.y = w0 * (bf2f(a0.y) + bf2f(b0.y)) + w1 * (bf2f(a1.y) + bf2f(b1.y));
  o.z = w0 * (bf2f(a0.z) + bf2f(b0.z)) + w1 * (bf2f(a1.z) + bf2f(b1.z));
  o.w = w0 * (bf2f(a0.w) + bf2f(b0.w)) + w1 * (bf2f(a1.w) + bf2f(b1.w));
  ((float4*)out)[(size_t)t * (D_ / 4) + i] = o;
}

// ---------------------------------------------------------------------------
extern "C" void kernel_launch(void* const* d_in, const int* in_sizes, int n_in,
                              void* d_out, int out_size, void* d_ws, size_t ws_size,
                              hipStream_t stream)
{
  const float* x   = (const float*)d_in[0];
  const float* rw  = (const float*)d_in[1];
  const float* rb  = (const float*)d_in[2];
  const float* w12 = (const float*)d_in[3];
  const float* w3  = (const float*)d_in[4];
  float* out = (float*)d_out;

  // workspace layout (~258 MB; capacity layout CAP_=16384 rows)
  char* wsb = (char*)d_ws;
  int*   counts    = (int*)(wsb + 0);                 // 8 ints
  int*   tile_e    = (int*)(wsb + 1024);              // 40 ints
  int*   tile_m0   = (int*)(wsb + 2048);              // 40 ints
  int*   expert_of = (int*)(wsb + 4096);              // 4096 ints (16 KB)
  int*   slot_of   = (int*)(wsb + 4096 + 16384);
  float* w_of      = (float*)(wsb + 4096 + 2 * 16384);
  int*   pair_row  = (int*)(wsb + 4096 + 3 * 16384);
  float* tok_ssq   = (float*)(wsb + 4096 + 4 * 16384);        // 2048 floats
  unsigned short* px   = (unsigned short*)(wsb + ((size_t)1   << 20));   // 32 MB
  unsigned short* hid  = (unsigned short*)(wsb + ((size_t)34  << 20));   // 64 MB
  unsigned short* w12t = (unsigned short*)(wsb + ((size_t)98  << 20));   // 64 MB
  unsigned short* w3t  = (unsigned short*)(wsb + ((size_t)162 << 20));   // 32 MB
  unsigned short* ybuf = (unsigned short*)(wsb + ((size_t)194 << 20));   // 64 MB

  transpose_all_kernel<<<1536, 512, 0, stream>>>(w12, w3, w12t, w3t, counts);
  router_pack_kernel<<<TOK_ / 4, 256, 0, stream>>>(x, rw, rb, counts, expert_of, slot_of, w_of, tok_ssq, px);
  meta_kernel<<<1, 256, 0, stream>>>(counts, tok_ssq, expert_of, slot_of, tile_e, tile_m0, pair_row, out + (size_t)TOK_ * D_);
  gemm1_kernel<<<dim3(16, MAXTILES_), 256, 0, stream>>>(px, w12t, hid, counts, tile_e, tile_m0);
  gemm2_kernel<<<dim3(8, MAXTILES_, 2), 256, 0, stream>>>(hid, w3t, counts, tile_e, tile_m0, ybuf);
  combine_kernel<<<TOK_, 256, 0, stream>>>(ybuf, pair_row, w_of, out);
}